// Round 3
// baseline (394.253 us; speedup 1.0000x reference)
//
#include <hip/hip_runtime.h>
#include <hip/hip_bf16.h>
#include <stdint.h>

typedef __hip_bfloat16 bf16;
typedef __attribute__((ext_vector_type(4))) float f32x4;
typedef __attribute__((ext_vector_type(8))) short short8;

#define SEQ   4096
#define CDIM  1024

// ---------------------------------------------------------------------------
// async global->LDS, 16B per lane. LDS dest = wave-uniform base + lane*16.
// ---------------------------------------------------------------------------
__device__ __forceinline__ void async_load16(const void* g, void* l) {
  auto gp = reinterpret_cast<const __attribute__((address_space(1))) uint32_t*>(
      reinterpret_cast<uintptr_t>(g));
  auto lp = reinterpret_cast<__attribute__((address_space(3))) uint32_t*>(
      static_cast<uint32_t>(reinterpret_cast<uintptr_t>(l)));
  __builtin_amdgcn_global_load_lds(gp, lp, 16, 0, 0);
}

// ---------------------------------------------------------------------------
// fp32 -> bf16 convert, 4 elems/thread
// ---------------------------------------------------------------------------
__global__ __launch_bounds__(256) void convert_kernel(const float* __restrict__ in,
                                                      bf16* __restrict__ out, int n4) {
  int i = blockIdx.x * 256 + threadIdx.x;
  if (i >= n4) return;
  float4 f = ((const float4*)in)[i];
  union { bf16 b[4]; ushort4 u; } c;
  c.b[0] = __float2bfloat16(f.x);
  c.b[1] = __float2bfloat16(f.y);
  c.b[2] = __float2bfloat16(f.z);
  c.b[3] = __float2bfloat16(f.w);
  ((ushort4*)out)[i] = c.u;
}

// ---------------------------------------------------------------------------
// m97-style bf16 GEMM, B^T input: C[m][n] = sum_k A[m][k] * B[n][k]
// 128x128 block tile, 4 waves (2x2 of 64x64), 4x4 MFMA 16x16x32 per wave.
// Operand-swap trick: D's M-dim (4 consecutive rows per reg quad) comes from
// the A operand. Feed W as A for Q/proj blocks, x as A for K/V blocks, so
// each lane's reg quad is contiguous in the target layout -> direct 8B/16B
// stores, no LDS staging.
// EPI=0: qkv epilogue -> Q [bh][n][d] (swapped), K^T/V^T [bh][d][n] (normal),
//        elu+1 on q/k.
// EPI=1: proj epilogue (swapped) -> fp32 out [t][c], float4 stores + bias.
// ---------------------------------------------------------------------------
template <int EPI>
__global__ __launch_bounds__(256) void gemm_bt(const bf16* __restrict__ A,
                                               const bf16* __restrict__ B,
                                               const float* __restrict__ bias,
                                               bf16* __restrict__ Qo,
                                               bf16* __restrict__ Ko,
                                               bf16* __restrict__ Vo,
                                               float* __restrict__ Out,
                                               const int K) {
  __shared__ unsigned short As[128 * 32];
  __shared__ unsigned short Bs[128 * 32];
  const int tid  = threadIdx.x;
  const int w    = tid >> 6, lane = tid & 63;
  const int wm   = w >> 1,   wn   = w & 1;
  const int lr   = lane & 15, lq  = lane >> 4;
  const int bm   = blockIdx.y, bn = blockIdx.x;

  const int rA  = lane >> 2;          // row within a 16-row chunk
  const int cA  = (lane & 3) * 8;     // col offset (elements)
  const int ci0 = w * 2;

  const bf16* Ag = A + ((size_t)(bm * 128 + ci0 * 16 + rA)) * K + cA;
  const bf16* Bg = B + ((size_t)(bn * 128 + ci0 * 16 + rA)) * K + cA;

  // swapped: W feeds the A (M) operand
  const bool swapped = (EPI == 1) || (bn < 8);
  const unsigned short* Af = swapped ? Bs : As;
  const unsigned short* Bf = swapped ? As : Bs;

  f32x4 acc[4][4] = {};

  for (int kt = 0; kt < K; kt += 32) {
    __syncthreads();
    async_load16(Ag + kt,                  As + (ci0    ) * 512);
    async_load16(Ag + kt + (size_t)16 * K, As + (ci0 + 1) * 512);
    async_load16(Bg + kt,                  Bs + (ci0    ) * 512);
    async_load16(Bg + kt + (size_t)16 * K, Bs + (ci0 + 1) * 512);
    __syncthreads();

    short8 af[4], bfr[4];
#pragma unroll
    for (int mt = 0; mt < 4; ++mt)
      af[mt] = *(const short8*)(Af + (wm * 64 + mt * 16 + lr) * 32 + lq * 8);
#pragma unroll
    for (int nt = 0; nt < 4; ++nt)
      bfr[nt] = *(const short8*)(Bf + (wn * 64 + nt * 16 + lr) * 32 + lq * 8);
#pragma unroll
    for (int mt = 0; mt < 4; ++mt)
#pragma unroll
      for (int nt = 0; nt < 4; ++nt)
        acc[mt][nt] = __builtin_amdgcn_mfma_f32_16x16x32_bf16(af[mt], bfr[nt], acc[mt][nt], 0, 0, 0);
  }

  if constexpr (EPI == 0) {
    if (swapped) {
      // Q block: m = channel j, col = token t. 4 regs = 4 consecutive d.
#pragma unroll
      for (int mt = 0; mt < 4; ++mt) {
        const int j0 = bn * 128 + wm * 64 + mt * 16 + lq * 4;
        const int h  = j0 >> 6, d0 = j0 & 63;
#pragma unroll
        for (int nt = 0; nt < 4; ++nt) {
          const int t = bm * 128 + wn * 64 + nt * 16 + lr;
          const int b = t >> 12, n = t & 4095;
          union { bf16 v[4]; ushort4 u; } pk;
#pragma unroll
          for (int r = 0; r < 4; ++r) {
            float v = acc[mt][nt][r];
            v = (v > 0.0f) ? (v + 1.0f) : __expf(v);
            pk.v[r] = __float2bfloat16(v);
          }
          *(ushort4*)(Qo + (((size_t)((b * 16 + h) * SEQ + n)) << 6) + d0) = pk.u;
        }
      }
    } else {
      // K/V block: m = token t, col = channel j. 4 regs = 4 consecutive n.
#pragma unroll
      for (int nt = 0; nt < 4; ++nt) {
        const int j   = bn * 128 + wn * 64 + nt * 16 + lr;
        const int sel = j >> 10;           // 1 or 2
        const int h   = (j >> 6) & 15;
        const int d   = j & 63;
        bf16* dst = (sel == 1) ? Ko : Vo;
#pragma unroll
        for (int mt = 0; mt < 4; ++mt) {
          const int t0 = bm * 128 + wm * 64 + mt * 16 + lq * 4;
          const int b = t0 >> 12, n0 = t0 & 4095;
          union { bf16 v[4]; ushort4 u; } pk;
#pragma unroll
          for (int r = 0; r < 4; ++r) {
            float v = acc[mt][nt][r];
            if (sel == 1) v = (v > 0.0f) ? (v + 1.0f) : __expf(v);
            pk.v[r] = __float2bfloat16(v);
          }
          *(ushort4*)(dst + ((size_t)((b * 16 + h) * 64 + d)) * SEQ + n0) = pk.u;
        }
      }
    }
  } else {
    // proj (swapped): m = channel j, col = token t. float4 stores.
#pragma unroll
    for (int mt = 0; mt < 4; ++mt) {
      const int j0 = bn * 128 + wm * 64 + mt * 16 + lq * 4;
      const float4 bv = *(const float4*)&bias[j0];
#pragma unroll
      for (int nt = 0; nt < 4; ++nt) {
        const int t = bm * 128 + wn * 64 + nt * 16 + lr;
        float4 o;
        o.x = acc[mt][nt][0] + bv.x;
        o.y = acc[mt][nt][1] + bv.y;
        o.z = acc[mt][nt][2] + bv.z;
        o.w = acc[mt][nt][3] + bv.w;
        *(float4*)&Out[(size_t)t * CDIM + j0] = o;
      }
    }
  }
}

// ---------------------------------------------------------------------------
// kv partials via MFMA.  Inputs K^T,V^T [bh][d][n] (n contiguous).
// grid (8 n-splits, 64 bh). Output KVp[split][bh][e][d] fp32 (transposed
// store: each lane's 4 acc values are 4 consecutive d -> float4).
// Also per-split ksum partials KSp[split][bh][d].
// ---------------------------------------------------------------------------
__global__ __launch_bounds__(256) void kv_mfma(const bf16* __restrict__ KT,
                                               const bf16* __restrict__ VT,
                                               float* __restrict__ KVp,
                                               float* __restrict__ KSp) {
  __shared__ bf16 kt[64 * 64];
  __shared__ bf16 vt[64 * 64];
  __shared__ float ksred[256];
  const int tid = threadIdx.x;
  const int w = tid >> 6, lane = tid & 63;
  const int wm = w >> 1, wn = w & 1;
  const int lr = lane & 15, lq = lane >> 4;
  const int sp = blockIdx.x, bh = blockIdx.y;
  const bf16* kg0 = KT + (size_t)bh * 64 * SEQ + sp * 512;
  const bf16* vg0 = VT + (size_t)bh * 64 * SEQ + sp * 512;

  f32x4 acc[2][2] = {};
  float kacc = 0.0f;
  const int ksd = tid & 63, ksq = tid >> 6;

  for (int nc = 0; nc < 8; ++nc) {
    __syncthreads();
#pragma unroll
    for (int i = 0; i < 2; ++i) {
      const int row = w * 16 + i * 8 + (lane >> 3);
      const int col = (lane & 7) * 8;
      async_load16(kg0 + (size_t)row * SEQ + nc * 64 + col, kt + (w * 16 + i * 8) * 64);
      async_load16(vg0 + (size_t)row * SEQ + nc * 64 + col, vt + (w * 16 + i * 8) * 64);
    }
    __syncthreads();

#pragma unroll
    for (int ks = 0; ks < 2; ++ks) {
      short8 a0 = *(const short8*)&kt[(wm * 32 +      lr) * 64 + ks * 32 + lq * 8];
      short8 a1 = *(const short8*)&kt[(wm * 32 + 16 + lr) * 64 + ks * 32 + lq * 8];
      short8 b0 = *(const short8*)&vt[(wn * 32 +      lr) * 64 + ks * 32 + lq * 8];
      short8 b1 = *(const short8*)&vt[(wn * 32 + 16 + lr) * 64 + ks * 32 + lq * 8];
      acc[0][0] = __builtin_amdgcn_mfma_f32_16x16x32_bf16(a0, b0, acc[0][0], 0, 0, 0);
      acc[0][1] = __builtin_amdgcn_mfma_f32_16x16x32_bf16(a0, b1, acc[0][1], 0, 0, 0);
      acc[1][0] = __builtin_amdgcn_mfma_f32_16x16x32_bf16(a1, b0, acc[1][0], 0, 0, 0);
      acc[1][1] = __builtin_amdgcn_mfma_f32_16x16x32_bf16(a1, b1, acc[1][1], 0, 0, 0);
    }
    // ksum partial: thread (d=tid&63, quarter=tid>>6) sums 16 n of kt row d
#pragma unroll
    for (int s = 0; s < 2; ++s) {
      short8 kk = *(const short8*)&kt[ksd * 64 + ksq * 16 + s * 8];
#pragma unroll
      for (int j = 0; j < 8; ++j)
        kacc += __bfloat162float(((const bf16*)&kk)[j]);
    }
  }

  // write kv partials transposed: KVp[sp][bh][e][d]
  float* outp = KVp + ((size_t)(sp * 64 + bh)) * 4096;
#pragma unroll
  for (int mt = 0; mt < 2; ++mt)
#pragma unroll
    for (int nt = 0; nt < 2; ++nt) {
      const int e  = wn * 32 + nt * 16 + lr;
      const int d0 = wm * 32 + mt * 16 + lq * 4;
      *(float4*)&outp[e * 64 + d0] = *(float4*)&acc[mt][nt];
    }
  ksred[tid] = kacc;
  __syncthreads();
  if (tid < 64) {
    float s = ksred[tid] + ksred[tid + 64] + ksred[tid + 128] + ksred[tid + 192];
    KSp[(sp * 64 + bh) * 64 + tid] = s;
  }
}

// ---------------------------------------------------------------------------
// reduce partials: KVT bf16 hi/lo [bh][e][128] (cols 0..63 hi, 64..127 lo),
// ksum fp32 [bh][64]. grid 64 blocks.
// ---------------------------------------------------------------------------
__global__ __launch_bounds__(256) void kv_reduce(const float* __restrict__ KVp,
                                                 const float* __restrict__ KSp,
                                                 bf16* __restrict__ KVT,
                                                 float* __restrict__ KS) {
  const int bh = blockIdx.x, t = threadIdx.x;
#pragma unroll 4
  for (int i = 0; i < 16; ++i) {
    const int idx = i * 256 + t;
    float s = 0.0f;
#pragma unroll
    for (int sp = 0; sp < 8; ++sp) s += KVp[((size_t)(sp * 64 + bh)) * 4096 + idx];
    const bf16 hi = __float2bfloat16(s);
    const float lo = s - __bfloat162float(hi);
    const int e = idx >> 6, d = idx & 63;
    KVT[(size_t)bh * 8192 + e * 128 + d]      = hi;
    KVT[(size_t)bh * 8192 + e * 128 + 64 + d] = __float2bfloat16(lo);
  }
  if (t < 64) {
    float s = 0.0f;
#pragma unroll
    for (int sp = 0; sp < 8; ++sp) s += KSp[(sp * 64 + bh) * 64 + t];
    KS[bh * 64 + t] = s;
  }
}

// ---------------------------------------------------------------------------
// num = q @ kv (MFMA, K=128 over hi/lo), den = q . ksum + 1e-8,
// attn[b][n][h*64+e] = num/den (bf16, coalesced via LDS transpose).
// grid (32 n-tiles of 128, 64 bh).
// ---------------------------------------------------------------------------
__global__ __launch_bounds__(256) void num_mfma(const bf16* __restrict__ Qb,
                                                const bf16* __restrict__ KVT,
                                                const float* __restrict__ KS,
                                                bf16* __restrict__ Attn) {
  __shared__ bf16 qs[128 * 64];     // [n][d]
  __shared__ bf16 kvs[64 * 128];    // [e][hi|lo d]
  __shared__ bf16 Cs[128 * 72];     // out staging, padded
  __shared__ float ksl[64];
  __shared__ float dred[256];
  __shared__ float den[128];
  const int tid = threadIdx.x;
  const int w = tid >> 6, lane = tid & 63;
  const int wm = w >> 1, wn = w & 1;
  const int lr = lane & 15, lq = lane >> 4;
  const int bh = blockIdx.y, n00 = blockIdx.x * 128;
  const int b = bh >> 4, h = bh & 15;

  const bf16* qg  = Qb  + ((size_t)bh * SEQ + n00) * 64;
  const bf16* kvg = KVT + (size_t)bh * 8192;
#pragma unroll
  for (int i = 0; i < 4; ++i) {
    const int row = w * 32 + i * 8 + (lane >> 3);
    async_load16(qg + (size_t)row * 64 + (lane & 7) * 8, qs + (w * 32 + i * 8) * 64);
  }
#pragma unroll
  for (int i = 0; i < 4; ++i) {
    const int row = w * 16 + i * 4 + (lane >> 4);
    async_load16(kvg + (size_t)row * 128 + (lane & 15) * 8, kvs + (w * 16 + i * 4) * 128);
  }
  if (tid < 64) ksl[tid] = KS[bh * 64 + tid];
  __syncthreads();

  // denominator partial: thread -> (n = tid>>1, half = tid&1), 32 d each
  {
    const int n = tid >> 1, half = tid & 1;
    float s = 0.0f;
#pragma unroll
    for (int v8 = 0; v8 < 4; ++v8) {
      short8 qq = *(const short8*)&qs[n * 64 + half * 32 + v8 * 8];
#pragma unroll
      for (int j = 0; j < 8; ++j)
        s += __bfloat162float(((const bf16*)&qq)[j]) * ksl[half * 32 + v8 * 8 + j];
    }
    dred[tid] = s;
  }

  // MFMA: wave tile 64n x 32e, K = 128 (hi|lo)
  short8 afr[4][2], bfr[2][4];
#pragma unroll
  for (int mt = 0; mt < 4; ++mt)
#pragma unroll
    for (int kh = 0; kh < 2; ++kh)
      afr[mt][kh] = *(const short8*)&qs[(wm * 64 + mt * 16 + lr) * 64 + kh * 32 + lq * 8];
#pragma unroll
  for (int nt = 0; nt < 2; ++nt)
#pragma unroll
    for (int ks = 0; ks < 4; ++ks)
      bfr[nt][ks] = *(const short8*)&kvs[(wn * 32 + nt * 16 + lr) * 128 + ks * 32 + lq * 8];

  f32x4 acc[4][2] = {};
#pragma unroll
  for (int ks = 0; ks < 4; ++ks)
#pragma unroll
    for (int mt = 0; mt < 4; ++mt)
#pragma unroll
      for (int nt = 0; nt < 2; ++nt)
        acc[mt][nt] = __builtin_amdgcn_mfma_f32_16x16x32_bf16(afr[mt][ks & 1], bfr[nt][ks],
                                                              acc[mt][nt], 0, 0, 0);
  __syncthreads();   // dred complete (qs/kvs reads also done)
  if (tid < 128) den[tid] = dred[tid * 2] + dred[tid * 2 + 1] + 1e-8f;
  __syncthreads();

  // epilogue: scale by 1/den, stage [n][e] in LDS, coalesced write
#pragma unroll
  for (int mt = 0; mt < 4; ++mt) {
#pragma unroll
    for (int r = 0; r < 4; ++r) {
      const int nl = wm * 64 + mt * 16 + lq * 4 + r;
      const float inv = 1.0f / den[nl];
#pragma unroll
      for (int nt = 0; nt < 2; ++nt) {
        const int e = wn * 32 + nt * 16 + lr;
        Cs[nl * 72 + e] = __float2bfloat16(acc[mt][nt][r] * inv);
      }
    }
  }
  __syncthreads();
#pragma unroll
  for (int it = 0; it < 4; ++it) {
    const int nl = it * 32 + (tid >> 3);
    const int ch = tid & 7;
    short8 val = *(const short8*)&Cs[nl * 72 + ch * 8];
    *(short8*)(Attn + ((size_t)(b * SEQ + n00 + nl)) * CDIM + h * 64 + ch * 8) = val;
  }
}

// ---------------------------------------------------------------------------
extern "C" void kernel_launch(void* const* d_in, const int* in_sizes, int n_in,
                              void* d_out, int out_size, void* d_ws, size_t ws_size,
                              hipStream_t stream) {
  const float* x      = (const float*)d_in[0];
  const float* w_qkv  = (const float*)d_in[1];
  const float* w_proj = (const float*)d_in[2];
  const float* b_proj = (const float*)d_in[3];
  float* out = (float*)d_out;
  char* ws = (char*)d_ws;

  // workspace layout (bytes)
  bf16*  xb     = (bf16*)(ws + 0);                    // 33.5 MB (dead after GEMM1)
  bf16*  wqkvb  = (bf16*)(ws + 33554432);
  bf16*  wprojb = (bf16*)(ws + 39845888);
  bf16*  qb     = (bf16*)(ws + 41943040);             // [bh][n][d]
  bf16*  ktb    = (bf16*)(ws + 75497472);             // [bh][d][n]
  bf16*  vtb    = (bf16*)(ws + 109051904);            // [bh][e][n]
  float* kvp    = (float*)(ws + 0);                   // 8 MB partials (alias xb)
  float* ksp    = (float*)(ws + 8388608);             // 128 KB
  bf16*  kvt    = (bf16*)(ws + 142606336);            // 1 MB [bh][e][hi|lo]
  float* ksum   = (float*)(ws + 143654912);           // 16 KB
  bf16*  attn   = (bf16*)(ws + 0);                    // alias (kvp dead by then)

  convert_kernel<<<16384, 256, 0, stream>>>(x,      xb,     16777216 / 4);
  convert_kernel<<<3072,  256, 0, stream>>>(w_qkv,  wqkvb,  3145728 / 4);
  convert_kernel<<<1024,  256, 0, stream>>>(w_proj, wprojb, 1048576 / 4);

  gemm_bt<0><<<dim3(24, 128), 256, 0, stream>>>(xb, wqkvb, nullptr, qb, ktb, vtb, nullptr, 1024);
  kv_mfma<<<dim3(8, 64), 256, 0, stream>>>(ktb, vtb, kvp, ksp);
  kv_reduce<<<64, 256, 0, stream>>>(kvp, ksp, kvt, ksum);
  num_mfma<<<dim3(32, 64), 256, 0, stream>>>(qb, kvt, ksum, attn);
  gemm_bt<1><<<dim3(8, 128), 256, 0, stream>>>(attn, wprojb, b_proj, nullptr, nullptr, nullptr, out, 1024);
}

// Round 4
// 380.195 us; speedup vs baseline: 1.0370x; 1.0370x over previous
//
#include <hip/hip_runtime.h>
#include <hip/hip_bf16.h>
#include <stdint.h>

typedef __hip_bfloat16 bf16;
typedef __attribute__((ext_vector_type(4))) float f32x4;
typedef __attribute__((ext_vector_type(8))) short short8;

#define SEQ   4096
#define CDIM  1024

// ---------------------------------------------------------------------------
// async global->LDS, 16B per lane. LDS dest = wave-uniform base + lane*16.
// ---------------------------------------------------------------------------
__device__ __forceinline__ void async_load16(const void* g, void* l) {
  auto gp = reinterpret_cast<const __attribute__((address_space(1))) uint32_t*>(
      reinterpret_cast<uintptr_t>(g));
  auto lp = reinterpret_cast<__attribute__((address_space(3))) uint32_t*>(
      static_cast<uint32_t>(reinterpret_cast<uintptr_t>(l)));
  __builtin_amdgcn_global_load_lds(gp, lp, 16, 0, 0);
}

// ---------------------------------------------------------------------------
// fused fp32 -> bf16 convert for x, w_qkv, w_proj (one launch)
// ranges (in float4): x 4194304 | w_qkv 786432 | w_proj 262144
// ---------------------------------------------------------------------------
__global__ __launch_bounds__(256) void convert3_kernel(const float* __restrict__ x,
                                                       const float* __restrict__ wq,
                                                       const float* __restrict__ wp,
                                                       bf16* __restrict__ xb,
                                                       bf16* __restrict__ wqb,
                                                       bf16* __restrict__ wpb) {
  int i = blockIdx.x * 256 + threadIdx.x;
  const float* src;
  bf16* dst;
  int off;
  if (i < 4194304)      { src = x;  dst = xb;  off = i; }
  else if (i < 4980736) { src = wq; dst = wqb; off = i - 4194304; }
  else                  { src = wp; dst = wpb; off = i - 4980736; }
  float4 f = ((const float4*)src)[off];
  union { bf16 b[4]; ushort4 u; } c;
  c.b[0] = __float2bfloat16(f.x);
  c.b[1] = __float2bfloat16(f.y);
  c.b[2] = __float2bfloat16(f.z);
  c.b[3] = __float2bfloat16(f.w);
  ((ushort4*)dst)[off] = c.u;
}

// ---------------------------------------------------------------------------
// m97-style bf16 GEMM, both inputs row-major K-contiguous:
//   C[m][n] = sum_k X[m][k] * W[n][k]
// 128x128 block tile, 4 waves (2x2 of 64x64), 4x4 MFMA 16x16x32 per wave.
// Operand-swap at STAGING time (uniform): for blocks whose output layout
// wants channel-major rows, W rows are staged into As (the M operand) and X
// rows into Bs. Fragment reads are fixed-address either way.
// EPI=0: qkv -> Q [bh][n][d] (swapped, bn<8), K^T/V^T [bh][d][n] (normal),
//        elu+1 on q/k, direct 8B stores.
// EPI=1: proj (non-swapped) -> fp32 out [t][c], coalesced scalar stores.
// ---------------------------------------------------------------------------
template <int EPI>
__global__ __launch_bounds__(256) void gemm_bt(const bf16* __restrict__ X,
                                               const bf16* __restrict__ W,
                                               const float* __restrict__ bias,
                                               bf16* __restrict__ Qo,
                                               bf16* __restrict__ Ko,
                                               bf16* __restrict__ Vo,
                                               float* __restrict__ Out,
                                               const int K) {
  __shared__ unsigned short As[128 * 32];
  __shared__ unsigned short Bs[128 * 32];
  const int tid  = threadIdx.x;
  const int w    = tid >> 6, lane = tid & 63;
  const int wm   = w >> 1,   wn   = w & 1;
  const int lr   = lane & 15, lq  = lane >> 4;
  const int bm   = blockIdx.y, bn = blockIdx.x;

  const int rA  = lane >> 2;          // row within a 16-row chunk
  const int cA  = (lane & 3) * 8;     // col offset (elements)
  const int ci0 = w * 2;

  const bool swapped = (EPI == 0) && (bn < 8);

  const bf16* Xg = X + ((size_t)(bm * 128 + ci0 * 16 + rA)) * K + cA;
  const bf16* Wg = W + ((size_t)(bn * 128 + ci0 * 16 + rA)) * K + cA;
  const bf16* Ag = swapped ? Wg : Xg;   // uniform select, once
  const bf16* Bg = swapped ? Xg : Wg;

  f32x4 acc[4][4] = {};

  for (int kt = 0; kt < K; kt += 32) {
    __syncthreads();
    async_load16(Ag + kt,                  As + (ci0    ) * 512);
    async_load16(Ag + kt + (size_t)16 * K, As + (ci0 + 1) * 512);
    async_load16(Bg + kt,                  Bs + (ci0    ) * 512);
    async_load16(Bg + kt + (size_t)16 * K, Bs + (ci0 + 1) * 512);
    __syncthreads();

    short8 af[4], bfr[4];
#pragma unroll
    for (int mt = 0; mt < 4; ++mt)
      af[mt] = *(const short8*)(As + (wm * 64 + mt * 16 + lr) * 32 + lq * 8);
#pragma unroll
    for (int nt = 0; nt < 4; ++nt)
      bfr[nt] = *(const short8*)(Bs + (wn * 64 + nt * 16 + lr) * 32 + lq * 8);
#pragma unroll
    for (int mt = 0; mt < 4; ++mt)
#pragma unroll
      for (int nt = 0; nt < 4; ++nt)
        acc[mt][nt] = __builtin_amdgcn_mfma_f32_16x16x32_bf16(af[mt], bfr[nt], acc[mt][nt], 0, 0, 0);
  }

  if constexpr (EPI == 0) {
    if (swapped) {
      // Q block: m = channel j, col = token t. 4 regs = 4 consecutive d.
#pragma unroll
      for (int mt = 0; mt < 4; ++mt) {
        const int j0 = bn * 128 + wm * 64 + mt * 16 + lq * 4;
        const int h  = j0 >> 6, d0 = j0 & 63;
#pragma unroll
        for (int nt = 0; nt < 4; ++nt) {
          const int t = bm * 128 + wn * 64 + nt * 16 + lr;
          const int b = t >> 12, n = t & 4095;
          union { bf16 v[4]; ushort4 u; } pk;
#pragma unroll
          for (int r = 0; r < 4; ++r) {
            float v = acc[mt][nt][r];
            v = (v > 0.0f) ? (v + 1.0f) : __expf(v);
            pk.v[r] = __float2bfloat16(v);
          }
          *(ushort4*)(Qo + (((size_t)((b * 16 + h) * SEQ + n)) << 6) + d0) = pk.u;
        }
      }
    } else {
      // K/V block: m = token t, col = channel j. 4 regs = 4 consecutive n.
#pragma unroll
      for (int nt = 0; nt < 4; ++nt) {
        const int j   = bn * 128 + wn * 64 + nt * 16 + lr;
        const int sel = j >> 10;           // 1 or 2
        const int h   = (j >> 6) & 15;
        const int d   = j & 63;
        bf16* dst = (sel == 1) ? Ko : Vo;
#pragma unroll
        for (int mt = 0; mt < 4; ++mt) {
          const int t0 = bm * 128 + wm * 64 + mt * 16 + lq * 4;
          const int b = t0 >> 12, n0 = t0 & 4095;
          union { bf16 v[4]; ushort4 u; } pk;
#pragma unroll
          for (int r = 0; r < 4; ++r) {
            float v = acc[mt][nt][r];
            if (sel == 1) v = (v > 0.0f) ? (v + 1.0f) : __expf(v);
            pk.v[r] = __float2bfloat16(v);
          }
          *(ushort4*)(dst + ((size_t)((b * 16 + h) * 64 + d)) * SEQ + n0) = pk.u;
        }
      }
    }
  } else {
    // proj (non-swapped): m = token t, col = channel. Coalesced scalar stores.
#pragma unroll
    for (int mt = 0; mt < 4; ++mt) {
#pragma unroll
      for (int r = 0; r < 4; ++r) {
        const int t = bm * 128 + wm * 64 + mt * 16 + lq * 4 + r;
        float* op = Out + (size_t)t * CDIM + bn * 128 + wn * 64 + lr;
#pragma unroll
        for (int nt = 0; nt < 4; ++nt)
          op[nt * 16] = acc[mt][nt][r] + bias[bn * 128 + wn * 64 + nt * 16 + lr];
      }
    }
  }
}

// ---------------------------------------------------------------------------
// kv partials via MFMA.  Inputs K^T,V^T [bh][d][n] (n contiguous).
// grid (8 n-splits, 64 bh). Output KVp[split][bh][e][d] fp32.
// ksum via MFMA against a ones B-fragment (no scalar reduction).
// ---------------------------------------------------------------------------
__global__ __launch_bounds__(256) void kv_mfma(const bf16* __restrict__ KT,
                                               const bf16* __restrict__ VT,
                                               float* __restrict__ KVp,
                                               float* __restrict__ KSp) {
  __shared__ bf16 kt[64 * 64];
  __shared__ bf16 vt[64 * 64];
  const int tid = threadIdx.x;
  const int w = tid >> 6, lane = tid & 63;
  const int wm = w >> 1, wn = w & 1;
  const int lr = lane & 15, lq = lane >> 4;
  const int sp = blockIdx.x, bh = blockIdx.y;
  const bf16* kg0 = KT + (size_t)bh * 64 * SEQ + sp * 512;
  const bf16* vg0 = VT + (size_t)bh * 64 * SEQ + sp * 512;

  f32x4 acc[2][2] = {};
  f32x4 kacc0 = {}, kacc1 = {};
  short8 ones;
#pragma unroll
  for (int j = 0; j < 8; ++j) ((unsigned short*)&ones)[j] = 0x3F80;  // bf16 1.0

  for (int nc = 0; nc < 8; ++nc) {
    __syncthreads();
#pragma unroll
    for (int i = 0; i < 2; ++i) {
      const int row = w * 16 + i * 8 + (lane >> 3);
      const int col = (lane & 7) * 8;
      async_load16(kg0 + (size_t)row * SEQ + nc * 64 + col, kt + (w * 16 + i * 8) * 64);
      async_load16(vg0 + (size_t)row * SEQ + nc * 64 + col, vt + (w * 16 + i * 8) * 64);
    }
    __syncthreads();

#pragma unroll
    for (int ks = 0; ks < 2; ++ks) {
      short8 a0 = *(const short8*)&kt[(wm * 32 +      lr) * 64 + ks * 32 + lq * 8];
      short8 a1 = *(const short8*)&kt[(wm * 32 + 16 + lr) * 64 + ks * 32 + lq * 8];
      short8 b0 = *(const short8*)&vt[(wn * 32 +      lr) * 64 + ks * 32 + lq * 8];
      short8 b1 = *(const short8*)&vt[(wn * 32 + 16 + lr) * 64 + ks * 32 + lq * 8];
      acc[0][0] = __builtin_amdgcn_mfma_f32_16x16x32_bf16(a0, b0, acc[0][0], 0, 0, 0);
      acc[0][1] = __builtin_amdgcn_mfma_f32_16x16x32_bf16(a0, b1, acc[0][1], 0, 0, 0);
      acc[1][0] = __builtin_amdgcn_mfma_f32_16x16x32_bf16(a1, b0, acc[1][0], 0, 0, 0);
      acc[1][1] = __builtin_amdgcn_mfma_f32_16x16x32_bf16(a1, b1, acc[1][1], 0, 0, 0);
      kacc0 = __builtin_amdgcn_mfma_f32_16x16x32_bf16(a0, ones, kacc0, 0, 0, 0);
      kacc1 = __builtin_amdgcn_mfma_f32_16x16x32_bf16(a1, ones, kacc1, 0, 0, 0);
    }
  }

  // write kv partials transposed: KVp[sp][bh][e][d]
  float* outp = KVp + ((size_t)(sp * 64 + bh)) * 4096;
#pragma unroll
  for (int mt = 0; mt < 2; ++mt)
#pragma unroll
    for (int nt = 0; nt < 2; ++nt) {
      const int e  = wn * 32 + nt * 16 + lr;
      const int d0 = wm * 32 + mt * 16 + lq * 4;
      *(float4*)&outp[e * 64 + d0] = *(float4*)&acc[mt][nt];
    }
  // ksum: D rows (m) = d; all 16 cols identical. wn==0 waves, col-0 lanes write.
  if (wn == 0 && lr == 0) {
    float* ksp = KSp + (size_t)(sp * 64 + bh) * 64 + wm * 32;
#pragma unroll
    for (int r = 0; r < 4; ++r) {
      ksp[lq * 4 + r]      = kacc0[r];
      ksp[16 + lq * 4 + r] = kacc1[r];
    }
  }
}

// ---------------------------------------------------------------------------
// reduce partials: KVT bf16 hi/lo [bh][e][128] (cols 0..63 hi, 64..127 lo),
// ksum fp32 [bh][64]. grid 64 blocks.
// ---------------------------------------------------------------------------
__global__ __launch_bounds__(256) void kv_reduce(const float* __restrict__ KVp,
                                                 const float* __restrict__ KSp,
                                                 bf16* __restrict__ KVT,
                                                 float* __restrict__ KS) {
  const int bh = blockIdx.x, t = threadIdx.x;
#pragma unroll 4
  for (int i = 0; i < 16; ++i) {
    const int idx = i * 256 + t;
    float s = 0.0f;
#pragma unroll
    for (int sp = 0; sp < 8; ++sp) s += KVp[((size_t)(sp * 64 + bh)) * 4096 + idx];
    const bf16 hi = __float2bfloat16(s);
    const float lo = s - __bfloat162float(hi);
    const int e = idx >> 6, d = idx & 63;
    KVT[(size_t)bh * 8192 + e * 128 + d]      = hi;
    KVT[(size_t)bh * 8192 + e * 128 + 64 + d] = __float2bfloat16(lo);
  }
  if (t < 64) {
    float s = 0.0f;
#pragma unroll
    for (int sp = 0; sp < 8; ++sp) s += KSp[(sp * 64 + bh) * 64 + t];
    KS[bh * 64 + t] = s;
  }
}

// ---------------------------------------------------------------------------
// num = q @ kv (MFMA, K=128 over hi/lo), den = q . ksum + 1e-8,
// attn[b][n][h*64+e] = num/den (bf16, coalesced via LDS transpose).
// grid (32 n-tiles of 128, 64 bh).
// ---------------------------------------------------------------------------
__global__ __launch_bounds__(256) void num_mfma(const bf16* __restrict__ Qb,
                                                const bf16* __restrict__ KVT,
                                                const float* __restrict__ KS,
                                                bf16* __restrict__ Attn) {
  __shared__ bf16 qs[128 * 64];     // [n][d]
  __shared__ bf16 kvs[64 * 128];    // [e][hi|lo d]
  __shared__ bf16 Cs[128 * 72];     // out staging, padded
  __shared__ float ksl[64];
  __shared__ float dred[256];
  __shared__ float den[128];
  const int tid = threadIdx.x;
  const int w = tid >> 6, lane = tid & 63;
  const int wm = w >> 1, wn = w & 1;
  const int lr = lane & 15, lq = lane >> 4;
  const int bh = blockIdx.y, n00 = blockIdx.x * 128;
  const int b = bh >> 4, h = bh & 15;

  const bf16* qg  = Qb  + ((size_t)bh * SEQ + n00) * 64;
  const bf16* kvg = KVT + (size_t)bh * 8192;
#pragma unroll
  for (int i = 0; i < 4; ++i) {
    const int row = w * 32 + i * 8 + (lane >> 3);
    async_load16(qg + (size_t)row * 64 + (lane & 7) * 8, qs + (w * 32 + i * 8) * 64);
  }
#pragma unroll
  for (int i = 0; i < 4; ++i) {
    const int row = w * 16 + i * 4 + (lane >> 4);
    async_load16(kvg + (size_t)row * 128 + (lane & 15) * 8, kvs + (w * 16 + i * 4) * 128);
  }
  if (tid < 64) ksl[tid] = KS[bh * 64 + tid];
  __syncthreads();

  // denominator partial: thread -> (n = tid>>1, half = tid&1), 32 d each
  {
    const int n = tid >> 1, half = tid & 1;
    float s = 0.0f;
#pragma unroll
    for (int v8 = 0; v8 < 4; ++v8) {
      short8 qq = *(const short8*)&qs[n * 64 + half * 32 + v8 * 8];
#pragma unroll
      for (int j = 0; j < 8; ++j)
        s += __bfloat162float(((const bf16*)&qq)[j]) * ksl[half * 32 + v8 * 8 + j];
    }
    dred[tid] = s;
  }

  // MFMA: wave tile 64n x 32e, K = 128 (hi|lo)
  short8 afr[4][2], bfr[2][4];
#pragma unroll
  for (int mt = 0; mt < 4; ++mt)
#pragma unroll
    for (int kh = 0; kh < 2; ++kh)
      afr[mt][kh] = *(const short8*)&qs[(wm * 64 + mt * 16 + lr) * 64 + kh * 32 + lq * 8];
#pragma unroll
  for (int nt = 0; nt < 2; ++nt)
#pragma unroll
    for (int ks = 0; ks < 4; ++ks)
      bfr[nt][ks] = *(const short8*)&kvs[(wn * 32 + nt * 16 + lr) * 128 + ks * 32 + lq * 8];

  f32x4 acc[4][2] = {};
#pragma unroll
  for (int ks = 0; ks < 4; ++ks)
#pragma unroll
    for (int mt = 0; mt < 4; ++mt)
#pragma unroll
      for (int nt = 0; nt < 2; ++nt)
        acc[mt][nt] = __builtin_amdgcn_mfma_f32_16x16x32_bf16(afr[mt][ks & 1], bfr[nt][ks],
                                                              acc[mt][nt], 0, 0, 0);
  __syncthreads();   // dred complete (qs/kvs reads also done)
  if (tid < 128) den[tid] = dred[tid * 2] + dred[tid * 2 + 1] + 1e-8f;
  __syncthreads();

  // epilogue: scale by 1/den, stage [n][e] in LDS, coalesced write
#pragma unroll
  for (int mt = 0; mt < 4; ++mt) {
#pragma unroll
    for (int r = 0; r < 4; ++r) {
      const int nl = wm * 64 + mt * 16 + lq * 4 + r;
      const float inv = 1.0f / den[nl];
#pragma unroll
      for (int nt = 0; nt < 2; ++nt) {
        const int e = wn * 32 + nt * 16 + lr;
        Cs[nl * 72 + e] = __float2bfloat16(acc[mt][nt][r] * inv);
      }
    }
  }
  __syncthreads();
#pragma unroll
  for (int it = 0; it < 4; ++it) {
    const int nl = it * 32 + (tid >> 3);
    const int ch = tid & 7;
    short8 val = *(const short8*)&Cs[nl * 72 + ch * 8];
    *(short8*)(Attn + ((size_t)(b * SEQ + n00 + nl)) * CDIM + h * 64 + ch * 8) = val;
  }
}

// ---------------------------------------------------------------------------
extern "C" void kernel_launch(void* const* d_in, const int* in_sizes, int n_in,
                              void* d_out, int out_size, void* d_ws, size_t ws_size,
                              hipStream_t stream) {
  const float* x      = (const float*)d_in[0];
  const float* w_qkv  = (const float*)d_in[1];
  const float* w_proj = (const float*)d_in[2];
  const float* b_proj = (const float*)d_in[3];
  float* out = (float*)d_out;
  char* ws = (char*)d_ws;

  // workspace layout (bytes)
  bf16*  xb     = (bf16*)(ws + 0);                    // 33.5 MB (dead after GEMM1)
  bf16*  wqkvb  = (bf16*)(ws + 33554432);
  bf16*  wprojb = (bf16*)(ws + 39845888);
  bf16*  qb     = (bf16*)(ws + 41943040);             // [bh][n][d]
  bf16*  ktb    = (bf16*)(ws + 75497472);             // [bh][d][n]
  bf16*  vtb    = (bf16*)(ws + 109051904);            // [bh][e][n]
  float* kvp    = (float*)(ws + 0);                   // 8 MB partials (alias xb)
  float* ksp    = (float*)(ws + 8388608);             // 128 KB
  bf16*  kvt    = (bf16*)(ws + 142606336);            // 1 MB [bh][e][hi|lo]
  float* ksum   = (float*)(ws + 143654912);           // 16 KB
  bf16*  attn   = (bf16*)(ws + 0);                    // alias (kvp dead by then)

  convert3_kernel<<<20480, 256, 0, stream>>>(x, w_qkv, w_proj, xb, wqkvb, wprojb);

  gemm_bt<0><<<dim3(24, 128), 256, 0, stream>>>(xb, wqkvb, nullptr, qb, ktb, vtb, nullptr, 1024);
  kv_mfma<<<dim3(8, 64), 256, 0, stream>>>(ktb, vtb, kvp, ksp);
  kv_reduce<<<64, 256, 0, stream>>>(kvp, ksp, kvt, ksum);
  num_mfma<<<dim3(32, 64), 256, 0, stream>>>(qb, kvt, ksum, attn);
  gemm_bt<1><<<dim3(8, 128), 256, 0, stream>>>(attn, wprojb, b_proj, nullptr, nullptr, nullptr, out, 1024);
}